// Round 4
// baseline (657.933 us; speedup 1.0000x reference)
//
#include <hip/hip_runtime.h>
#include <hip/hip_bf16.h>

#define DEVI __device__ __forceinline__

typedef __attribute__((ext_vector_type(4))) float f32x4;
typedef __attribute__((ext_vector_type(8))) short bf16x8;

// Problem sizes
#define BB 4
#define SS 2048
#define DD 1024
#define MTOK (BB*SS)   // 8192

// Workspace layout (bytes)
#define OFF_XB  0ull
#define OFF_WB  (OFF_XB + (size_t)MTOK*DD*2)        // x bf16: 16 MB
#define OFF_Q   (OFF_WB + (size_t)3*DD*DD*2)        // W stacked bf16: 6 MB
#define OFF_K   (OFF_Q  + (size_t)MTOK*DD*2)
#define OFF_VT  (OFF_K  + (size_t)MTOK*DD*2)
#define OFF_P   (OFF_VT + (size_t)MTOK*DD*2)
#define OFF_LP  (OFF_P  + (size_t)BB*SS*SS*2)       // P bf16: 33.5 MB
#define OFF_L   (OFF_LP + (size_t)BB*16*2*SS*4)     // Lpart f32 [b][kt][wn][q]: 1 MB
#define WS_NEED (OFF_L  + (size_t)BB*SS*4)          // ~108 MB

DEVI void gload16(const __hip_bfloat16* g, __hip_bfloat16* l) {
  __builtin_amdgcn_global_load_lds(
      (const __attribute__((address_space(1))) unsigned int*)(const void*)g,
      (__attribute__((address_space(3))) unsigned int*)(void*)l, 16, 0, 0);
}

// LDS tile layout (both cores): [rows][4 slots of 16B]; global slot s of row r
// stored at lds slot s ^ ((r>>1)&3). Staged via pre-swizzled global source
// (global_load_lds dest is linear), read back with the same XOR. 0 conflicts
// (verified r3).
DEVI bf16x8 fragread(const __hip_bfloat16* base, int row, int lg) {
  int slot = lg ^ ((row >> 1) & 3);
  return *reinterpret_cast<const bf16x8*>(base + row * 32 + slot * 8);
}

// ======================= r3 4-wave 128x128 core (pv_out) ====================
DEVI void stage32(const __hip_bfloat16* __restrict__ g, int ldg,
                  __hip_bfloat16* dst, int tid) {
  int w = tid >> 6, l = tid & 63;
  int r = l >> 2, slot = (l & 3) ^ ((l >> 3) & 3);
#pragma unroll
  for (int i = 0; i < 2; i++) {
    int c = w * 2 + i;
    gload16(g + (size_t)(c * 16 + r) * ldg + slot * 8, dst + c * 512);
  }
}

DEVI void gemm_core(const __hip_bfloat16* __restrict__ A, int lda,
                    const __hip_bfloat16* __restrict__ B, int ldb,
                    int NT, __hip_bfloat16* lds, int tid, f32x4 acc[4][4]) {
  int lane = tid & 63, lr = lane & 15, lg = lane >> 4;
  int w = tid >> 6, wm = w >> 1, wn = w & 1;

  stage32(A, lda, lds + 0 * 8192, tid);
  stage32(B, ldb, lds + 0 * 8192 + 4096, tid);
  stage32(A + 32, lda, lds + 1 * 8192, tid);
  stage32(B + 32, ldb, lds + 1 * 8192 + 4096, tid);

  for (int t = 0; t < NT; ++t) {
    if (t + 1 < NT) asm volatile("s_waitcnt vmcnt(4)" ::: "memory");
    else            asm volatile("s_waitcnt vmcnt(0)" ::: "memory");
    asm volatile("s_barrier" ::: "memory");

    const __hip_bfloat16* cA = lds + (t % 3) * 8192;
    const __hip_bfloat16* cB = cA + 4096;
    __hip_bfloat16* nA = lds + ((t + 2) % 3) * 8192;
    bool st = (t + 2) < NT;

    bf16x8 bfr[4], af[4];
#pragma unroll
    for (int ni = 0; ni < 4; ni++) bfr[ni] = fragread(cB, wn * 64 + ni * 16 + lr, lg);
#pragma unroll
    for (int mi = 0; mi < 2; mi++) af[mi] = fragread(cA, wm * 64 + mi * 16 + lr, lg);
    if (st) stage32(A + (size_t)(t + 2) * 32, lda, nA, tid);
    __builtin_amdgcn_s_setprio(1);
#pragma unroll
    for (int mi = 0; mi < 2; mi++)
#pragma unroll
      for (int ni = 0; ni < 4; ni++)
        acc[mi][ni] = __builtin_amdgcn_mfma_f32_16x16x32_bf16(af[mi], bfr[ni], acc[mi][ni], 0, 0, 0);
    __builtin_amdgcn_s_setprio(0);

#pragma unroll
    for (int mi = 2; mi < 4; mi++) af[mi] = fragread(cA, wm * 64 + mi * 16 + lr, lg);
    if (st) stage32(B + (size_t)(t + 2) * 32, ldb, nA + 4096, tid);
    __builtin_amdgcn_s_setprio(1);
#pragma unroll
    for (int mi = 2; mi < 4; mi++)
#pragma unroll
      for (int ni = 0; ni < 4; ni++)
        acc[mi][ni] = __builtin_amdgcn_mfma_f32_16x16x32_bf16(af[mi], bfr[ni], acc[mi][ni], 0, 0, 0);
    __builtin_amdgcn_s_setprio(0);

    asm volatile("s_waitcnt lgkmcnt(0)" ::: "memory");
    __builtin_amdgcn_sched_barrier(0);
  }
}

// ================== new 8-wave 256x128 core (qkv, qk_scores) ================
// LDS buffer: A[256][32] (8192 elems) + B[128][32] (4096) = 12288 elems/buf,
// double-buffered = 48 KB -> 3 blocks/CU, 6 waves/SIMD.
#define BUF2 12288

DEVI void stageA2(const __hip_bfloat16* __restrict__ g, int ldg,
                  __hip_bfloat16* dst, int tid) {
  int w = tid >> 6, l = tid & 63;
  int r = l >> 2, slot = (l & 3) ^ ((l >> 3) & 3);
#pragma unroll
  for (int i = 0; i < 2; i++) {
    int c = w * 2 + i;  // 16 chunks of 16 rows
    gload16(g + (size_t)(c * 16 + r) * ldg + slot * 8, dst + c * 512);
  }
}

DEVI void stageB2(const __hip_bfloat16* __restrict__ g, int ldg,
                  __hip_bfloat16* dst, int tid) {
  int w = tid >> 6, l = tid & 63;
  int r = l >> 2, slot = (l & 3) ^ ((l >> 3) & 3);
  gload16(g + (size_t)(w * 16 + r) * ldg + slot * 8, dst + w * 512);  // 8 chunks
}

// 8 waves: wm = w>>1 (0..3, 64-row strips of 256), wn = w&1 (0..1, 64-col of 128).
// Issue-early staging: stage t+1 before reading/compute of t; vmcnt(0)+barrier
// at iteration end (drain covered by ~16 MFMA + 8 ds_read of compute).
DEVI void gemm_core2(const __hip_bfloat16* __restrict__ A, int lda,
                     const __hip_bfloat16* __restrict__ B, int ldb,
                     int NT, __hip_bfloat16* lds, int tid, f32x4 acc[4][4]) {
  int lane = tid & 63, lr = lane & 15, lg = lane >> 4;
  int w = tid >> 6, wm = w >> 1, wn = w & 1;

  stageA2(A, lda, lds, tid);
  stageB2(B, ldb, lds + 8192, tid);
  asm volatile("s_waitcnt vmcnt(0)" ::: "memory");
  __builtin_amdgcn_s_barrier();

  for (int t = 0; t < NT; ++t) {
    const __hip_bfloat16* cur = lds + (t & 1) * BUF2;
    __hip_bfloat16* nxt = lds + ((t + 1) & 1) * BUF2;
    if (t + 1 < NT) {
      stageA2(A + (size_t)(t + 1) * 32, lda, nxt, tid);
      stageB2(B + (size_t)(t + 1) * 32, ldb, nxt + 8192, tid);
    }
    bf16x8 af[4], bfr[4];
#pragma unroll
    for (int mi = 0; mi < 4; mi++) af[mi] = fragread(cur, wm * 64 + mi * 16 + lr, lg);
#pragma unroll
    for (int ni = 0; ni < 4; ni++) bfr[ni] = fragread(cur + 8192, wn * 64 + ni * 16 + lr, lg);
    __builtin_amdgcn_s_setprio(1);
#pragma unroll
    for (int mi = 0; mi < 4; mi++)
#pragma unroll
      for (int ni = 0; ni < 4; ni++)
        acc[mi][ni] = __builtin_amdgcn_mfma_f32_16x16x32_bf16(af[mi], bfr[ni], acc[mi][ni], 0, 0, 0);
    __builtin_amdgcn_s_setprio(0);
    // my t+1 stages landed; my cur ds_reads already retired (MFMA dataflow)
    asm volatile("s_waitcnt vmcnt(0)" ::: "memory");
    __builtin_amdgcn_s_barrier();
  }
}

// ============================== cast kernels ================================
__global__ void cast_f32_bf16(const float* __restrict__ src,
                              __hip_bfloat16* __restrict__ dst, int n) {
  int i = (blockIdx.x * blockDim.x + threadIdx.x) * 4;
  if (i >= n) return;
  float4 v = *reinterpret_cast<const float4*>(src + i);
  __hip_bfloat16 h[4] = {__float2bfloat16(v.x), __float2bfloat16(v.y),
                         __float2bfloat16(v.z), __float2bfloat16(v.w)};
  *reinterpret_cast<uint2*>(dst + i) = *reinterpret_cast<const uint2*>(h);
}

__global__ void cast_w3(const float* __restrict__ Wq, const float* __restrict__ Wk,
                        const float* __restrict__ Wv, __hip_bfloat16* __restrict__ dst) {
  int i = (blockIdx.x * blockDim.x + threadIdx.x) * 4;  // over 3*DD*DD
  const int n1 = DD * DD;
  const float* src = (i < n1) ? Wq : (i < 2 * n1 ? Wk : Wv);
  int off = (i < n1) ? i : (i < 2 * n1 ? i - n1 : i - 2 * n1);
  float4 v = *reinterpret_cast<const float4*>(src + off);
  __hip_bfloat16 h[4] = {__float2bfloat16(v.x), __float2bfloat16(v.y),
                         __float2bfloat16(v.z), __float2bfloat16(v.w)};
  *reinterpret_cast<uint2*>(dst + i) = *reinterpret_cast<const uint2*>(h);
}

// ============================ gemm_qkv (256x128) ============================
// grid: 768 blocks (1D, XCD-swizzled); block tile 256 rows x 128 cols.
__launch_bounds__(512, 6)
__global__ void gemm_qkv(const __hip_bfloat16* __restrict__ xb,
                         const __hip_bfloat16* __restrict__ Wb,
                         __hip_bfloat16* __restrict__ Q,
                         __hip_bfloat16* __restrict__ Kb,
                         __hip_bfloat16* __restrict__ Vt) {
  __shared__ __hip_bfloat16 lds[2 * BUF2];
  int id = blockIdx.x;
  int swz = (id & 7) * 96 + (id >> 3);  // 768 % 8 == 0: bijective XCD swizzle
  int mt = swz / 24, nt = swz % 24;
  int tid = threadIdx.x, lane = tid & 63, lr = lane & 15, lg = lane >> 4;
  int w = tid >> 6, wm = w >> 1, wn = w & 1;
  f32x4 acc[4][4];
  f32x4 zero = {0.f, 0.f, 0.f, 0.f};
#pragma unroll
  for (int i = 0; i < 4; i++)
#pragma unroll
    for (int j = 0; j < 4; j++) acc[i][j] = zero;

  gemm_core2(xb + (size_t)mt * 256 * 1024, 1024,
             Wb + (size_t)nt * 128 * 1024, 1024, 32, lds, tid, acc);

  int which = nt >> 3;                  // 0=Q, 1=K, 2=V
  int ncol0 = (nt & 7) * 128 + wn * 64;
  int mrow0 = mt * 256 + wm * 64;
#pragma unroll
  for (int mi = 0; mi < 4; mi++)
#pragma unroll
    for (int ni = 0; ni < 4; ni++)
#pragma unroll
      for (int r = 0; r < 4; r++) {
        int row = mrow0 + mi * 16 + lg * 4 + r;
        int col = ncol0 + ni * 16 + lr;
        __hip_bfloat16 hv = __float2bfloat16(acc[mi][ni][r]);
        if (which == 0)      Q[(size_t)row * 1024 + col] = hv;
        else if (which == 1) Kb[(size_t)row * 1024 + col] = hv;
        else {
          int b = row >> 11, s = row & 2047;
          Vt[((size_t)b * 1024 + col) * 2048 + s] = hv;
        }
      }
}

// =========================== qk_scores (256x128) ============================
// grid (kt=16, qt=8, b=4); causal: skip blocks with kt*128 > qt*256+255.
__launch_bounds__(512, 6)
__global__ void qk_scores(const __hip_bfloat16* __restrict__ Q,
                          const __hip_bfloat16* __restrict__ Kb,
                          __hip_bfloat16* __restrict__ P,
                          float* __restrict__ Lpart) {
  int kt = blockIdx.x, qt = blockIdx.y, b = blockIdx.z;
  if (kt > 2 * qt + 1) return;
  __shared__ __hip_bfloat16 lds[2 * BUF2];
  int tid = threadIdx.x, lane = tid & 63, lr = lane & 15, lg = lane >> 4;
  int w = tid >> 6, wm = w >> 1, wn = w & 1;
  f32x4 acc[4][4];
  f32x4 zero = {0.f, 0.f, 0.f, 0.f};
#pragma unroll
  for (int i = 0; i < 4; i++)
#pragma unroll
    for (int j = 0; j < 4; j++) acc[i][j] = zero;

  gemm_core2(Q + ((size_t)b * 2048 + qt * 256) * 1024, 1024,
             Kb + ((size_t)b * 2048 + kt * 128) * 1024, 1024, 32, lds, tid, acc);

  const float scale = 0.03125f;  // 1/sqrt(1024)
  float part[4][4];
#pragma unroll
  for (int i = 0; i < 4; i++)
#pragma unroll
    for (int r = 0; r < 4; r++) part[i][r] = 0.f;

  __hip_bfloat16* Pb = P + (size_t)b * 2048 * 2048;
#pragma unroll
  for (int mi = 0; mi < 4; mi++)
#pragma unroll
    for (int ni = 0; ni < 4; ni++)
#pragma unroll
      for (int r = 0; r < 4; r++) {
        int q = qt * 256 + wm * 64 + mi * 16 + lg * 4 + r;
        int k = kt * 128 + wn * 64 + ni * 16 + lr;
        float p = (k <= q) ? __expf(acc[mi][ni][r] * scale) : 0.f;
        __hip_bfloat16 hv = __float2bfloat16(p);
        Pb[(size_t)q * 2048 + k] = hv;
        part[mi][r] += __bfloat162float(hv);
      }

#pragma unroll
  for (int mi = 0; mi < 4; mi++)
#pragma unroll
    for (int r = 0; r < 4; r++) {
      float s = part[mi][r];
      s += __shfl_xor(s, 1); s += __shfl_xor(s, 2);
      s += __shfl_xor(s, 4); s += __shfl_xor(s, 8);
      part[mi][r] = s;
    }
  if (lr < 4) {
#pragma unroll
    for (int mi = 0; mi < 4; mi++) {
      int q = qt * 256 + wm * 64 + mi * 16 + lg * 4 + lr;
      Lpart[(((size_t)b * 16 + kt) * 2 + wn) * 2048 + q] = part[mi][lr];
    }
  }
}

__global__ void reduce_L(const float* __restrict__ Lpart, float* __restrict__ L) {
  int i = blockIdx.x * 256 + threadIdx.x;  // [0, 8192)
  int b = i >> 11, q = i & 2047;
  int nkt = (q >> 7) + 1;
  float s = 0.f;
  for (int kt = 0; kt < nkt; kt++) {
    s += Lpart[(((size_t)b * 16 + kt) * 2 + 0) * 2048 + q];
    s += Lpart[(((size_t)b * 16 + kt) * 2 + 1) * 2048 + q];
  }
  L[i] = s;
}

// ============================ pv_out (r3 128x128) ===========================
__launch_bounds__(256, 3)
__global__ void pv_out(const __hip_bfloat16* __restrict__ P,
                       const __hip_bfloat16* __restrict__ Vt,
                       const float* __restrict__ L,
                       float* __restrict__ out) {
  int dt = blockIdx.x, qt = blockIdx.y, b = blockIdx.z;
  __shared__ __hip_bfloat16 lds[3 * 8192];
  int tid = threadIdx.x, lane = tid & 63, lr = lane & 15, lg = lane >> 4;
  int w = tid >> 6, wm = w >> 1, wn = w & 1;
  f32x4 acc[4][4];
  f32x4 zero = {0.f, 0.f, 0.f, 0.f};
#pragma unroll
  for (int i = 0; i < 4; i++)
#pragma unroll
    for (int j = 0; j < 4; j++) acc[i][j] = zero;

  gemm_core(P + (size_t)b * 2048 * 2048 + (size_t)qt * 128 * 2048, 2048,
            Vt + (size_t)b * 1024 * 2048 + (size_t)dt * 128 * 2048, 2048,
            (qt + 1) * 4, lds, tid, acc);

#pragma unroll
  for (int mi = 0; mi < 4; mi++)
#pragma unroll
    for (int r = 0; r < 4; r++) {
      int q = qt * 128 + wm * 64 + mi * 16 + lg * 4 + r;
      float inv = 1.f / L[(size_t)b * 2048 + q];
#pragma unroll
      for (int ni = 0; ni < 4; ni++) {
        int d = dt * 128 + wn * 64 + ni * 16 + lr;
        out[((size_t)b * 2048 + q) * 1024 + d] = acc[mi][ni][r] * inv;
      }
    }
}

extern "C" void kernel_launch(void* const* d_in, const int* in_sizes, int n_in,
                              void* d_out, int out_size, void* d_ws, size_t ws_size,
                              hipStream_t stream) {
  const float* x  = (const float*)d_in[0];
  const float* Wq = (const float*)d_in[1];
  const float* Wk = (const float*)d_in[2];
  const float* Wv = (const float*)d_in[3];
  float* out = (float*)d_out;
  char* ws = (char*)d_ws;
  if (ws_size < WS_NEED) return;

  __hip_bfloat16* xb = (__hip_bfloat16*)(ws + OFF_XB);
  __hip_bfloat16* Wb = (__hip_bfloat16*)(ws + OFF_WB);
  __hip_bfloat16* Q  = (__hip_bfloat16*)(ws + OFF_Q);
  __hip_bfloat16* Kb = (__hip_bfloat16*)(ws + OFF_K);
  __hip_bfloat16* Vt = (__hip_bfloat16*)(ws + OFF_VT);
  __hip_bfloat16* P  = (__hip_bfloat16*)(ws + OFF_P);
  float* Lpart = (float*)(ws + OFF_LP);
  float* L     = (float*)(ws + OFF_L);

  cast_f32_bf16<<<8192, 256, 0, stream>>>(x, xb, MTOK * DD);
  cast_w3<<<3072, 256, 0, stream>>>(Wq, Wk, Wv, Wb);

  gemm_qkv<<<768, 512, 0, stream>>>(xb, Wb, Q, Kb, Vt);
  qk_scores<<<dim3(16, 8, 4), 512, 0, stream>>>(Q, Kb, P, Lpart);
  reduce_L<<<32, 256, 0, stream>>>(Lpart, L);
  pv_out<<<dim3(8, 16, 4), 256, 0, stream>>>(P, Vt, L, out);
}

// Round 5
// 194.998 us; speedup vs baseline: 3.3741x; 3.3741x over previous
//
#include <hip/hip_runtime.h>
#include <hip/hip_bf16.h>

#define DEVI __device__ __forceinline__

typedef __attribute__((ext_vector_type(4))) float f32x4;
typedef __attribute__((ext_vector_type(8))) short bf16x8;

// Problem sizes
#define BB 4
#define SS 2048
#define DD 1024
#define MTOK (BB*SS)   // 8192

// Workspace layout (bytes)
#define OFF_XB  0ull
#define OFF_WB  (OFF_XB + (size_t)MTOK*DD*2)        // x bf16: 16 MB
#define OFF_Q   (OFF_WB + (size_t)3*DD*DD*2)        // W stacked bf16: 6 MB
#define OFF_K   (OFF_Q  + (size_t)MTOK*DD*2)
#define OFF_VT  (OFF_K  + (size_t)MTOK*DD*2)
#define OFF_P   (OFF_VT + (size_t)MTOK*DD*2)
#define OFF_LP  (OFF_P  + (size_t)BB*SS*SS*2)       // P bf16: 33.5 MB
#define OFF_L   (OFF_LP + (size_t)BB*16*2*SS*4)     // Lpart f32 [b][kt][wn][q]: 1 MB
#define WS_NEED (OFF_L  + (size_t)BB*SS*4)          // ~108 MB

DEVI void gload16(const __hip_bfloat16* g, __hip_bfloat16* l) {
  __builtin_amdgcn_global_load_lds(
      (const __attribute__((address_space(1))) unsigned int*)(const void*)g,
      (__attribute__((address_space(3))) unsigned int*)(void*)l, 16, 0, 0);
}

// LDS tile layout: [rows][4 slots of 16B]; global slot s of row r stored at
// lds slot s ^ ((r>>1)&3). Staged via pre-swizzled global source addresses
// (global_load_lds dest is linear), read back with the same XOR.
// Verified 0 bank conflicts in r3.
DEVI bf16x8 fragread(const __hip_bfloat16* base, int row, int lg) {
  int slot = lg ^ ((row >> 1) & 3);
  return *reinterpret_cast<const bf16x8*>(base + row * 32 + slot * 8);
}

// Stage a 128x32 bf16 tile (2 loads/thread, 256 threads / 4 waves).
DEVI void stageB3(const __hip_bfloat16* __restrict__ g, int ldg,
                  __hip_bfloat16* dst, int tid) {
  int w = tid >> 6, l = tid & 63;
  int r = l >> 2, slot = (l & 3) ^ ((l >> 3) & 3);
#pragma unroll
  for (int i = 0; i < 2; i++) {
    int c = w * 2 + i;  // 16-row chunk, wave-uniform LDS base
    gload16(g + (size_t)(c * 16 + r) * ldg + slot * 8, dst + c * 512);
  }
}

// Stage a 256x32 bf16 tile (4 loads/thread, 256 threads / 4 waves).
DEVI void stageA3(const __hip_bfloat16* __restrict__ g, int ldg,
                  __hip_bfloat16* dst, int tid) {
  int w = tid >> 6, l = tid & 63;
  int r = l >> 2, slot = (l & 3) ^ ((l >> 3) & 3);
#pragma unroll
  for (int i = 0; i < 4; i++) {
    int c = w * 4 + i;
    gload16(g + (size_t)(c * 16 + r) * ldg + slot * 8, dst + c * 512);
  }
}

// ============ 4-wave 256x128 core, per-wave 128x64 (acc[8][4]) ==============
// BK=32, triple-buffered LDS (3 x 12288 elems = 72 KB), 2-tiles-ahead
// prefetch, counted vmcnt(6) at tile boundaries (6 loads/thread/tile in
// flight), ONE barrier per K-tile, 2 phases of 16 MFMA with ds_read + stage
// interleaved, setprio around MFMA clusters.
//
// Safety: tile t+2 staged during iter t into buf[(t+2)%3], which held tile
// t-1 — all waves' t-1 ds_reads retired before end-of-(t-1) barrier
// (lgkmcnt(0)+sched_barrier precedes it). Boundary vmcnt(6) forces tile t+1
// (oldest 6 in-flight loads) landed; barrier publishes to all waves.
#define BUF3 12288

DEVI void gemm_core3(const __hip_bfloat16* __restrict__ A, int lda,
                     const __hip_bfloat16* __restrict__ B, int ldb,
                     int NT, __hip_bfloat16* lds, int tid, f32x4 acc[8][4]) {
  int lane = tid & 63, lr = lane & 15, lg = lane >> 4;
  int w = tid >> 6, wm = w >> 1, wn = w & 1;

  // prologue: stage tiles 0,1 (12 loads/thread); force tile 0 landed.
  stageA3(A, lda, lds + 0 * BUF3, tid);
  stageB3(B, ldb, lds + 0 * BUF3 + 8192, tid);
  stageA3(A + 32, lda, lds + 1 * BUF3, tid);
  stageB3(B + 32, ldb, lds + 1 * BUF3 + 8192, tid);
  asm volatile("s_waitcnt vmcnt(6)" ::: "memory");
  __builtin_amdgcn_s_barrier();

  for (int t = 0; t < NT; ++t) {
    const __hip_bfloat16* cA = lds + (t % 3) * BUF3;
    const __hip_bfloat16* cB = cA + 8192;
    __hip_bfloat16* nx = lds + ((t + 2) % 3) * BUF3;
    bool st = (t + 2) < NT;

    bf16x8 af[8], bfr[4];
    // ---- phase 1: frags (mi 0-3 + all B), stage next A, 16 MFMA ----
#pragma unroll
    for (int mi = 0; mi < 4; mi++) af[mi] = fragread(cA, wm * 128 + mi * 16 + lr, lg);
#pragma unroll
    for (int ni = 0; ni < 4; ni++) bfr[ni] = fragread(cB, wn * 64 + ni * 16 + lr, lg);
    if (st) stageA3(A + (size_t)(t + 2) * 32, lda, nx, tid);
    asm volatile("s_waitcnt lgkmcnt(0)" ::: "memory");
    __builtin_amdgcn_sched_barrier(0);
    __builtin_amdgcn_s_setprio(1);
#pragma unroll
    for (int mi = 0; mi < 4; mi++)
#pragma unroll
      for (int ni = 0; ni < 4; ni++)
        acc[mi][ni] = __builtin_amdgcn_mfma_f32_16x16x32_bf16(af[mi], bfr[ni], acc[mi][ni], 0, 0, 0);
    __builtin_amdgcn_s_setprio(0);

    // ---- phase 2: frags (mi 4-7), stage next B, 16 MFMA ----
#pragma unroll
    for (int mi = 4; mi < 8; mi++) af[mi] = fragread(cA, wm * 128 + mi * 16 + lr, lg);
    if (st) stageB3(B + (size_t)(t + 2) * 32, ldb, nx + 8192, tid);
    asm volatile("s_waitcnt lgkmcnt(0)" ::: "memory");
    __builtin_amdgcn_sched_barrier(0);
    __builtin_amdgcn_s_setprio(1);
#pragma unroll
    for (int mi = 4; mi < 8; mi++)
#pragma unroll
      for (int ni = 0; ni < 4; ni++)
        acc[mi][ni] = __builtin_amdgcn_mfma_f32_16x16x32_bf16(af[mi], bfr[ni], acc[mi][ni], 0, 0, 0);
    __builtin_amdgcn_s_setprio(0);

    // ---- boundary: force tile t+1 landed; leave t+2's 6 loads in flight ----
    if (t + 2 < NT) asm volatile("s_waitcnt vmcnt(6)" ::: "memory");
    else            asm volatile("s_waitcnt vmcnt(0)" ::: "memory");
    __builtin_amdgcn_s_barrier();
  }
}

// ============================== cast kernels ================================
__global__ void cast_f32_bf16(const float* __restrict__ src,
                              __hip_bfloat16* __restrict__ dst, int n) {
  int i = (blockIdx.x * blockDim.x + threadIdx.x) * 4;
  if (i >= n) return;
  float4 v = *reinterpret_cast<const float4*>(src + i);
  __hip_bfloat16 h[4] = {__float2bfloat16(v.x), __float2bfloat16(v.y),
                         __float2bfloat16(v.z), __float2bfloat16(v.w)};
  *reinterpret_cast<uint2*>(dst + i) = *reinterpret_cast<const uint2*>(h);
}

__global__ void cast_w3(const float* __restrict__ Wq, const float* __restrict__ Wk,
                        const float* __restrict__ Wv, __hip_bfloat16* __restrict__ dst) {
  int i = (blockIdx.x * blockDim.x + threadIdx.x) * 4;  // over 3*DD*DD
  const int n1 = DD * DD;
  const float* src = (i < n1) ? Wq : (i < 2 * n1 ? Wk : Wv);
  int off = (i < n1) ? i : (i < 2 * n1 ? i - n1 : i - 2 * n1);
  float4 v = *reinterpret_cast<const float4*>(src + off);
  __hip_bfloat16 h[4] = {__float2bfloat16(v.x), __float2bfloat16(v.y),
                         __float2bfloat16(v.z), __float2bfloat16(v.w)};
  *reinterpret_cast<uint2*>(dst + i) = *reinterpret_cast<const uint2*>(h);
}

// ============================ gemm_qkv (256x128) ============================
// grid: 768 blocks (mt 32 x nt 24), 1D XCD-swizzled (768 % 8 == 0).
__launch_bounds__(256, 2)
__global__ void gemm_qkv(const __hip_bfloat16* __restrict__ xb,
                         const __hip_bfloat16* __restrict__ Wb,
                         __hip_bfloat16* __restrict__ Q,
                         __hip_bfloat16* __restrict__ Kb,
                         __hip_bfloat16* __restrict__ Vt) {
  __shared__ __hip_bfloat16 lds[3 * BUF3];
  int id = blockIdx.x;
  int swz = (id & 7) * 96 + (id >> 3);
  int mt = swz / 24, nt = swz % 24;
  int tid = threadIdx.x, lane = tid & 63, lr = lane & 15, lg = lane >> 4;
  int w = tid >> 6, wm = w >> 1, wn = w & 1;
  f32x4 acc[8][4];
  f32x4 zero = {0.f, 0.f, 0.f, 0.f};
#pragma unroll
  for (int i = 0; i < 8; i++)
#pragma unroll
    for (int j = 0; j < 4; j++) acc[i][j] = zero;

  gemm_core3(xb + (size_t)mt * 256 * 1024, 1024,
             Wb + (size_t)nt * 128 * 1024, 1024, 32, lds, tid, acc);

  int which = nt >> 3;                  // 0=Q, 1=K, 2=V
  int ncol0 = (nt & 7) * 128 + wn * 64;
  int mrow0 = mt * 256 + wm * 128;
#pragma unroll
  for (int mi = 0; mi < 8; mi++)
#pragma unroll
    for (int ni = 0; ni < 4; ni++)
#pragma unroll
      for (int r = 0; r < 4; r++) {
        int row = mrow0 + mi * 16 + lg * 4 + r;
        int col = ncol0 + ni * 16 + lr;
        __hip_bfloat16 hv = __float2bfloat16(acc[mi][ni][r]);
        if (which == 0)      Q[(size_t)row * 1024 + col] = hv;
        else if (which == 1) Kb[(size_t)row * 1024 + col] = hv;
        else {
          int b = row >> 11, s = row & 2047;
          Vt[((size_t)b * 1024 + col) * 2048 + s] = hv;
        }
      }
}

// =========================== qk_scores (256x128) ============================
// grid (kt=16, qt=8, b=4); causal: skip blocks with kt*128 > qt*256+255.
__launch_bounds__(256, 2)
__global__ void qk_scores(const __hip_bfloat16* __restrict__ Q,
                          const __hip_bfloat16* __restrict__ Kb,
                          __hip_bfloat16* __restrict__ P,
                          float* __restrict__ Lpart) {
  int kt = blockIdx.x, qt = blockIdx.y, b = blockIdx.z;
  if (kt > 2 * qt + 1) return;
  __shared__ __hip_bfloat16 lds[3 * BUF3];
  int tid = threadIdx.x, lane = tid & 63, lr = lane & 15, lg = lane >> 4;
  int w = tid >> 6, wm = w >> 1, wn = w & 1;
  f32x4 acc[8][4];
  f32x4 zero = {0.f, 0.f, 0.f, 0.f};
#pragma unroll
  for (int i = 0; i < 8; i++)
#pragma unroll
    for (int j = 0; j < 4; j++) acc[i][j] = zero;

  gemm_core3(Q + ((size_t)b * 2048 + qt * 256) * 1024, 1024,
             Kb + ((size_t)b * 2048 + kt * 128) * 1024, 1024, 32, lds, tid, acc);

  const float scale = 0.03125f;  // 1/sqrt(1024)
  float part[8][4];
#pragma unroll
  for (int i = 0; i < 8; i++)
#pragma unroll
    for (int r = 0; r < 4; r++) part[i][r] = 0.f;

  __hip_bfloat16* Pb = P + (size_t)b * 2048 * 2048;
#pragma unroll
  for (int mi = 0; mi < 8; mi++)
#pragma unroll
    for (int ni = 0; ni < 4; ni++)
#pragma unroll
      for (int r = 0; r < 4; r++) {
        int q = qt * 256 + wm * 128 + mi * 16 + lg * 4 + r;
        int k = kt * 128 + wn * 64 + ni * 16 + lr;
        float p = (k <= q) ? __expf(acc[mi][ni][r] * scale) : 0.f;
        __hip_bfloat16 hv = __float2bfloat16(p);
        Pb[(size_t)q * 2048 + k] = hv;
        part[mi][r] += __bfloat162float(hv);
      }

#pragma unroll
  for (int mi = 0; mi < 8; mi++)
#pragma unroll
    for (int r = 0; r < 4; r++) {
      float s = part[mi][r];
      s += __shfl_xor(s, 1); s += __shfl_xor(s, 2);
      s += __shfl_xor(s, 4); s += __shfl_xor(s, 8);
      part[mi][r] = s;
    }
  if (lr < 4) {
#pragma unroll
    for (int mi = 0; mi < 8; mi++) {
      int q = qt * 256 + wm * 128 + mi * 16 + lg * 4 + lr;
      Lpart[(((size_t)b * 16 + kt) * 2 + wn) * 2048 + q] = part[mi][lr];
    }
  }
}

__global__ void reduce_L(const float* __restrict__ Lpart, float* __restrict__ L) {
  int i = blockIdx.x * 256 + threadIdx.x;  // [0, 8192)
  int b = i >> 11, q = i & 2047;
  int nkt = (q >> 7) + 1;
  float s = 0.f;
  for (int kt = 0; kt < nkt; kt++) {
    s += Lpart[(((size_t)b * 16 + kt) * 2 + 0) * 2048 + q];
    s += Lpart[(((size_t)b * 16 + kt) * 2 + 1) * 2048 + q];
  }
  L[i] = s;
}

// ============================= pv_out (256x128) =============================
// grid (dt=8, qt=8, b=4); K = (qt+1)*256 -> NT = (qt+1)*8 K-tiles.
__launch_bounds__(256, 2)
__global__ void pv_out(const __hip_bfloat16* __restrict__ P,
                       const __hip_bfloat16* __restrict__ Vt,
                       const float* __restrict__ L,
                       float* __restrict__ out) {
  int dt = blockIdx.x, qt = blockIdx.y, b = blockIdx.z;
  __shared__ __hip_bfloat16 lds[3 * BUF3];
  int tid = threadIdx.x, lane = tid & 63, lr = lane & 15, lg = lane >> 4;
  int w = tid >> 6, wm = w >> 1, wn = w & 1;
  f32x4 acc[8][4];
  f32x4 zero = {0.f, 0.f, 0.f, 0.f};
#pragma unroll
  for (int i = 0; i < 8; i++)
#pragma unroll
    for (int j = 0; j < 4; j++) acc[i][j] = zero;

  gemm_core3(P + (size_t)b * 2048 * 2048 + (size_t)qt * 256 * 2048, 2048,
             Vt + (size_t)b * 1024 * 2048 + (size_t)dt * 128 * 2048, 2048,
             (qt + 1) * 8, lds, tid, acc);

#pragma unroll
  for (int mi = 0; mi < 8; mi++)
#pragma unroll
    for (int r = 0; r < 4; r++) {
      int q = qt * 256 + wm * 128 + mi * 16 + lg * 4 + r;  // batch-local row
      float inv = 1.f / L[(size_t)b * 2048 + q];
#pragma unroll
      for (int ni = 0; ni < 4; ni++) {
        int d = dt * 128 + wn * 64 + ni * 16 + lr;
        out[((size_t)b * 2048 + q) * 1024 + d] = acc[mi][ni][r] * inv;
      }
    }
}

extern "C" void kernel_launch(void* const* d_in, const int* in_sizes, int n_in,
                              void* d_out, int out_size, void* d_ws, size_t ws_size,
                              hipStream_t stream) {
  const float* x  = (const float*)d_in[0];
  const float* Wq = (const float*)d_in[1];
  const float* Wk = (const float*)d_in[2];
  const float* Wv = (const float*)d_in[3];
  float* out = (float*)d_out;
  char* ws = (char*)d_ws;
  if (ws_size < WS_NEED) return;

  __hip_bfloat16* xb = (__hip_bfloat16*)(ws + OFF_XB);
  __hip_bfloat16* Wb = (__hip_bfloat16*)(ws + OFF_WB);
  __hip_bfloat16* Q  = (__hip_bfloat16*)(ws + OFF_Q);
  __hip_bfloat16* Kb = (__hip_bfloat16*)(ws + OFF_K);
  __hip_bfloat16* Vt = (__hip_bfloat16*)(ws + OFF_VT);
  __hip_bfloat16* P  = (__hip_bfloat16*)(ws + OFF_P);
  float* Lpart = (float*)(ws + OFF_LP);
  float* L     = (float*)(ws + OFF_L);

  cast_f32_bf16<<<8192, 256, 0, stream>>>(x, xb, MTOK * DD);
  cast_w3<<<3072, 256, 0, stream>>>(Wq, Wk, Wv, Wb);

  gemm_qkv<<<768, 256, 0, stream>>>(xb, Wb, Q, Kb, Vt);
  qk_scores<<<dim3(16, 8, 4), 256, 0, stream>>>(Q, Kb, P, Lpart);
  reduce_L<<<32, 256, 0, stream>>>(Lpart, L);
  pv_out<<<dim3(8, 8, 4), 256, 0, stream>>>(P, Vt, L, out);
}